// Round 6
// baseline (6792.818 us; speedup 1.0000x reference)
//
#include <hip/hip_runtime.h>

// Problem constants (T,B,D,H = 512,32,512,512; bidirectional)
#define TT    512
#define BB    32
#define HH    512
#define NBLK  64           // one block owns 8 hidden units of BOTH directions
#define NTHR  128          // 2 waves

typedef __attribute__((ext_vector_type(8))) short short8;
typedef __attribute__((ext_vector_type(4))) float f32x4;
typedef __attribute__((ext_vector_type(4))) unsigned u32x4;
typedef __attribute__((ext_vector_type(2))) unsigned u32x2;

#define SELH 0x05040100u
#define SELL 0x07060302u
#define GOLD 0x9E3779B9u

__device__ __forceinline__ ushort bf16_rne(float v) {
    unsigned u = __builtin_bit_cast(unsigned, v);
    unsigned r = u + 0x7FFFu + ((u >> 16) & 1u);
    return (ushort)(r >> 16);
}
__device__ __forceinline__ float bf16_to_f(ushort h) {
    unsigned u = ((unsigned)h) << 16;
    return __builtin_bit_cast(float, u);
}
__device__ __forceinline__ unsigned keyof(int s) { return (unsigned)(s + 1) * GOLD; }
__device__ __forceinline__ float xpf(unsigned u) {
    return bf16_to_f((ushort)(u & 0xFFFF)) + bf16_to_f((ushort)(u >> 16));
}

#define LDT(dst, PB, OFF) \
    asm volatile("global_load_dwordx4 %0, %1, off offset:%c2 sc0 sc1" \
                 : "=v"(dst) : "v"(PB), "i"(OFF) : "memory")
#define LDP4(dst, P) \
    asm volatile("global_load_dwordx4 %0, %1, off" : "=v"(dst) : "v"(P) : "memory")
#define WAIT_VM(N) do { asm volatile("s_waitcnt vmcnt(" #N ")" ::: "memory"); \
                        __builtin_amdgcn_sched_barrier(0); } while (0)

// one k-step: lane's 8 tagged elems (64 B) = 4 dwordx4
#define ISSUE_K(BUF, PB, KS) do { \
    LDT(BUF[0], PB, (KS)*256+ 0); LDT(BUF[1], PB, (KS)*256+16); \
    LDT(BUF[2], PB, (KS)*256+32); LDT(BUF[3], PB, (KS)*256+48); \
} while (0)

__device__ __forceinline__ bool k_ok(const u32x4* buf, unsigned key) {
    unsigned bad = 0u;
    #pragma unroll
    for (int i = 0; i < 4; ++i)
        bad |= (buf[i][0] ^ buf[i][1] ^ key) | (buf[i][2] ^ buf[i][3] ^ key);
    return __all((bad == 0u) ? 1 : 0) != 0;
}

__device__ __forceinline__ void st_tag2(unsigned* p, unsigned pay, unsigned chk) {
    u32x2 v = { pay, chk };
    asm volatile("global_store_dwordx2 %0, %1, off sc0 sc1" :: "v"(p), "v"(v) : "memory");
}
__device__ __forceinline__ void st_f(float* p, float v) {
    asm volatile("global_store_dword %0, %1, off" :: "v"(p), "v"(v) : "memory");
}

// ---------------------------------------------------------------------------
// Pre-pass GEMM (unchanged from r5, flags removed): XP[d][blk][t][b][slot],
// slot = jl*4+q for gate g = q*512 + blk*8 + jl.
// ---------------------------------------------------------------------------
__global__ void __launch_bounds__(256, 1)
xpre_gemm(const float* __restrict__ x, const float* __restrict__ W_ih,
          unsigned* __restrict__ XP) {
    __shared__ __align__(16) char sA[32768];
    __shared__ __align__(16) char sB[32768];
    const int tid = threadIdx.x;
    const int bid = blockIdx.x;
    const int d  = bid & 1;
    const int nt = (bid >> 1) & 15;
    const int mt = bid >> 5;
    const int lane = tid & 63, wid = tid >> 6;
    const int wm = wid >> 1, wn = wid & 1;
    const int lr = lane & 15, lk8 = (lane >> 4) * 8;

    f32x4 acc[16];
    #pragma unroll
    for (int i = 0; i < 16; ++i) acc[i] = (f32x4){0.f, 0.f, 0.f, 0.f};

    const float* Ab = x + (size_t)(mt * 128) * 512;
    const float* Bb = W_ih + ((size_t)d * 2048 + nt * 128) * 512;

    for (int kc = 0; kc < 8; ++kc) {
        #pragma unroll
        for (int i = 0; i < 8; ++i) {
            int f = i * 256 + tid;
            int row = f >> 4, fc = f & 15;
            int byte = (row * 128 + fc * 8) ^ ((row & 7) << 4);
            f32x4 va = *(const f32x4*)(Ab + (size_t)row * 512 + kc * 64 + fc * 4);
            f32x4 vb = *(const f32x4*)(Bb + (size_t)row * 512 + kc * 64 + fc * 4);
            ushort h0 = bf16_rne(va[0]), h1 = bf16_rne(va[1]), h2 = bf16_rne(va[2]), h3 = bf16_rne(va[3]);
            ushort l0 = bf16_rne(va[0] - bf16_to_f(h0)), l1 = bf16_rne(va[1] - bf16_to_f(h1));
            ushort l2 = bf16_rne(va[2] - bf16_to_f(h2)), l3 = bf16_rne(va[3] - bf16_to_f(h3));
            *(u32x2*)(sA + byte)         = (u32x2){ (unsigned)h0 | ((unsigned)h1 << 16),
                                                    (unsigned)h2 | ((unsigned)h3 << 16) };
            *(u32x2*)(sA + 16384 + byte) = (u32x2){ (unsigned)l0 | ((unsigned)l1 << 16),
                                                    (unsigned)l2 | ((unsigned)l3 << 16) };
            h0 = bf16_rne(vb[0]); h1 = bf16_rne(vb[1]); h2 = bf16_rne(vb[2]); h3 = bf16_rne(vb[3]);
            l0 = bf16_rne(vb[0] - bf16_to_f(h0)); l1 = bf16_rne(vb[1] - bf16_to_f(h1));
            l2 = bf16_rne(vb[2] - bf16_to_f(h2)); l3 = bf16_rne(vb[3] - bf16_to_f(h3));
            *(u32x2*)(sB + byte)         = (u32x2){ (unsigned)h0 | ((unsigned)h1 << 16),
                                                    (unsigned)h2 | ((unsigned)h3 << 16) };
            *(u32x2*)(sB + 16384 + byte) = (u32x2){ (unsigned)l0 | ((unsigned)l1 << 16),
                                                    (unsigned)l2 | ((unsigned)l3 << 16) };
        }
        __syncthreads();
        #pragma unroll
        for (int ks = 0; ks < 2; ++ks) {
            short8 bh[4], bl[4];
            #pragma unroll
            for (int ns = 0; ns < 4; ++ns) {
                int brow = wn * 64 + ns * 16 + lr;
                int byte = (brow * 128 + (ks * 32 + lk8) * 2) ^ ((brow & 7) << 4);
                bh[ns] = *(const short8*)(sB + byte);
                bl[ns] = *(const short8*)(sB + 16384 + byte);
            }
            #pragma unroll
            for (int ms = 0; ms < 4; ++ms) {
                int arow = wm * 64 + ms * 16 + lr;
                int byte = (arow * 128 + (ks * 32 + lk8) * 2) ^ ((arow & 7) << 4);
                short8 ah = *(const short8*)(sA + byte);
                short8 al = *(const short8*)(sA + 16384 + byte);
                #pragma unroll
                for (int ns = 0; ns < 4; ++ns) {
                    acc[ms*4+ns] = __builtin_amdgcn_mfma_f32_16x16x32_bf16(ah, bh[ns], acc[ms*4+ns], 0,0,0);
                    acc[ms*4+ns] = __builtin_amdgcn_mfma_f32_16x16x32_bf16(al, bh[ns], acc[ms*4+ns], 0,0,0);
                    acc[ms*4+ns] = __builtin_amdgcn_mfma_f32_16x16x32_bf16(ah, bl[ns], acc[ms*4+ns], 0,0,0);
                }
            }
        }
        __syncthreads();
    }
    #pragma unroll
    for (int ms = 0; ms < 4; ++ms)
    #pragma unroll
    for (int ns = 0; ns < 4; ++ns)
    #pragma unroll
    for (int r = 0; r < 4; ++r) {
        float v = acc[ms*4+ns][r];
        int m = mt * 128 + wm * 64 + ms * 16 + (lane >> 4) * 4 + r;
        int n = nt * 128 + wn * 64 + ns * 16 + lr;
        int t = m >> 5, b = m & 31;
        int q = n >> 9, rem = n & 511, bk = rem >> 3, jl = rem & 7;
        ushort hi = bf16_rne(v);
        ushort lo = bf16_rne(v - bf16_to_f(hi));
        XP[((((size_t)d * 64 + bk) * 512 + t) * 32 + b) * 32 + (jl * 4 + q)] =
            (unsigned)hi | ((unsigned)lo << 16);
    }
}

// ---------------------------------------------------------------------------
// Dual-direction persistent recurrence: 64 blocks x 128 thr; each block owns
// 8 j of BOTH directions (W_hh slices for both stationary in 128 KB LDS).
// Tagged {pay, pay^key(s)} h-exchange via MALL; the two directions' phases
// interleave so each publish gets ~1.5-2 us of other-direction work before
// its consumers check — checksum passes first try, retry path is rare.
// ---------------------------------------------------------------------------
__global__ void __launch_bounds__(NTHR, 1)
lstm_persist(const float* __restrict__ h0, const float* __restrict__ c0,
             const float* __restrict__ W_hh, const float* __restrict__ b_ih,
             const float* __restrict__ b_hh, const unsigned* __restrict__ XP,
             unsigned* __restrict__ h_tag, float* __restrict__ out) {
    __shared__ __align__(16) char sW[131072];  // [dir][plane][32 slots][512 k]
    __shared__ float sC[32][33];
    __shared__ float sBias[2][32];

    const int tid = threadIdx.x, blk = blockIdx.x, j0 = blk * 8;

    // ---- stage W_hh slices for both directions (swizzled bf16 hi/lo) ----
    for (int idx = tid; idx < 2 * 32 * 512; idx += NTHR) {
        int dir = idx >> 14, rem = idx & 16383;
        int r = rem >> 9, col = rem & 511;
        int jl = r >> 2, q = r & 3, g = q * 512 + j0 + jl;
        float v = W_hh[((size_t)dir * 2048 + g) * 512 + col];
        ushort hi = bf16_rne(v), lo = bf16_rne(v - bf16_to_f(hi));
        int byte = (r * 1024 + col * 2) ^ ((r & 7) << 4);
        *(ushort*)(sW + dir * 65536 + byte)         = hi;
        *(ushort*)(sW + dir * 65536 + 32768 + byte) = lo;
    }
    if (tid < 64) {
        int dir = tid >> 5, sl = tid & 31;
        int jl = sl >> 2, q = sl & 3, g = q * 512 + j0 + jl;
        sBias[dir][sl] = b_ih[dir * 2048 + g] + b_hh[dir * 2048 + g];
    }

    // ---- per-thread owned state: (b_own, jl_own) x {jl, jl+4} x {dir0,dir1}
    const int b_own = tid >> 2, jl_own = tid & 3;
    float cr0[2], hr0[2], cr1[2], hr1[2];
    #pragma unroll
    for (int v = 0; v < 2; ++v) {
        int j = j0 + jl_own + v * 4;
        cr0[v] = c0[(0 * BB + b_own) * HH + j];
        hr0[v] = h0[(0 * BB + b_own) * HH + j];
        cr1[v] = c0[(1 * BB + b_own) * HH + j];
        hr1[v] = h0[(1 * BB + b_own) * HH + j];
        ushort a = bf16_rne(hr0[v]), bq = bf16_rne(hr0[v] - bf16_to_f(a));
        unsigned pay0 = (unsigned)a | ((unsigned)bq << 16);
        a = bf16_rne(hr1[v]); bq = bf16_rne(hr1[v] - bf16_to_f(a));
        unsigned pay1 = (unsigned)a | ((unsigned)bq << 16);
        st_tag2(h_tag + ((size_t)(0 * 2 + 0) * 32 + b_own) * 1024 + j * 2, pay0, pay0 ^ keyof(0));
        st_tag2(h_tag + ((size_t)(0 * 2 + 1) * 32 + b_own) * 1024 + j * 2, pay1, pay1 ^ keyof(0));
    }
    __syncthreads();   // drains everything; sW/sBias ready

    const int lane = tid & 63, w = tid >> 6;
    const int lr = lane & 15, lk8 = (lane >> 4) * 8;
    const int brow = w * 16 + lr;

    u32x4 RA[4], RB[4], RC[4], RD[4];
    u32x4 xp0A, xp0B, xp1A, xp1B;
    bool clean = true;

    // MFMA one k-step from a validated tagged buffer
    auto mfma_k = [&](const u32x4* buf, int ks, int wof, f32x4& A0, f32x4& A1) {
        unsigned p0 = buf[0][0], p1 = buf[0][2], p2 = buf[1][0], p3 = buf[1][2];
        unsigned p4 = buf[2][0], p5 = buf[2][2], p6 = buf[3][0], p7 = buf[3][2];
        u32x4 hh = { __builtin_amdgcn_perm(p1, p0, SELH), __builtin_amdgcn_perm(p3, p2, SELH),
                     __builtin_amdgcn_perm(p5, p4, SELH), __builtin_amdgcn_perm(p7, p6, SELH) };
        u32x4 ll = { __builtin_amdgcn_perm(p1, p0, SELL), __builtin_amdgcn_perm(p3, p2, SELL),
                     __builtin_amdgcn_perm(p5, p4, SELL), __builtin_amdgcn_perm(p7, p6, SELL) };
        short8 ah = __builtin_bit_cast(short8, hh);
        short8 al = __builtin_bit_cast(short8, ll);
        int k2 = (ks * 32 + lk8) * 2;
        int by0 = wof + ((lr * 1024 + k2) ^ ((lr & 7) << 4));
        int by1 = wof + (((16 + lr) * 1024 + k2) ^ ((lr & 7) << 4));
        short8 bh0 = *(const short8*)(sW + by0);
        short8 bl0 = *(const short8*)(sW + by0 + 32768);
        short8 bh1 = *(const short8*)(sW + by1);
        short8 bl1 = *(const short8*)(sW + by1 + 32768);
        A0 = __builtin_amdgcn_mfma_f32_16x16x32_bf16(ah, bh0, A0, 0, 0, 0);
        A1 = __builtin_amdgcn_mfma_f32_16x16x32_bf16(ah, bh1, A1, 0, 0, 0);
        A0 = __builtin_amdgcn_mfma_f32_16x16x32_bf16(al, bh0, A0, 0, 0, 0);
        A1 = __builtin_amdgcn_mfma_f32_16x16x32_bf16(al, bh1, A1, 0, 0, 0);
        A0 = __builtin_amdgcn_mfma_f32_16x16x32_bf16(ah, bl0, A0, 0, 0, 0);
        A1 = __builtin_amdgcn_mfma_f32_16x16x32_bf16(ah, bl1, A1, 0, 0, 0);
    };

    // epilogue for one direction: sC roundtrip, activations, publish
    auto epilogue = [&](int dir, int t_eff, int pn, unsigned nkey,
                        const u32x4& xpA, const u32x4& xpB,
                        const f32x4& A0, const f32x4& A1, float* cr, float* hr) {
        #pragma unroll
        for (int r = 0; r < 4; ++r) {
            int row = w * 16 + (lane >> 4) * 4 + r;
            sC[row][lr]      = A0[r];
            sC[row][16 + lr] = A1[r];
        }
        asm volatile("s_waitcnt lgkmcnt(0)" ::: "memory");
        __builtin_amdgcn_sched_barrier(0);
        __builtin_amdgcn_s_barrier();
        __builtin_amdgcn_sched_barrier(0);
        #pragma unroll
        for (int v = 0; v < 2; ++v) {
            int jl = jl_own + v * 4;
            const u32x4& xp = v ? xpB : xpA;
            float gi = sC[b_own][jl*4+0] + sBias[dir][jl*4+0] + xpf(xp[0]);
            float gf = sC[b_own][jl*4+1] + sBias[dir][jl*4+1] + xpf(xp[1]);
            float gg = sC[b_own][jl*4+2] + sBias[dir][jl*4+2] + xpf(xp[2]);
            float go = sC[b_own][jl*4+3] + sBias[dir][jl*4+3] + xpf(xp[3]);
            float ig = 1.f / (1.f + expf(-gi));
            float fg = 1.f / (1.f + expf(-gf));
            float gt = tanhf(gg);
            float og = 1.f / (1.f + expf(-go));
            cr[v] = fg * cr[v] + ig * gt;
            hr[v] = og * tanhf(cr[v]);
            int j = j0 + jl;
            ushort a = bf16_rne(hr[v]), bq = bf16_rne(hr[v] - bf16_to_f(a));
            unsigned pay = (unsigned)a | ((unsigned)bq << 16);
            st_tag2(h_tag + ((size_t)(pn * 2 + dir) * 32 + b_own) * 1024 + j * 2,
                    pay, pay ^ nkey);
            st_f(out + ((size_t)t_eff * BB + b_own) * 1024 + dir * 512 + j, hr[v]);
        }
        asm volatile("s_waitcnt lgkmcnt(0)" ::: "memory");
        __builtin_amdgcn_sched_barrier(0);
        __builtin_amdgcn_s_barrier();
        __builtin_amdgcn_sched_barrier(0);
    };

// consume step: wait (ledger or safe-drain), validate, mfma, ring-issue next
#define CS(BUF, KS, NL, DOI, KS2, A0, A1) do { \
    if (clean) { WAIT_VM(NL); } else { WAIT_VM(0); } \
    if (!k_ok(BUF, key)) { \
        clean = false; \
        do { __builtin_amdgcn_s_sleep(1); ISSUE_K(BUF, pbc, KS); WAIT_VM(0); } \
        while (!k_ok(BUF, key)); \
    } \
    mfma_k(BUF, KS, wof, A0, A1); \
    if (DOI) { ISSUE_K(BUF, pbc, KS2); } \
} while (0)

#define CONSUME_DIR(PBX, WOF, A0, A1) do { \
    const unsigned* pbc = (PBX); const int wof = (WOF); \
    CS(RA, 0, 16, 1,  4, A0, A1); CS(RB, 1, 16, 1,  5, A0, A1); \
    CS(RC, 2, 16, 1,  6, A0, A1); CS(RD, 3, 16, 1,  7, A0, A1); \
    CS(RA, 4, 16, 1,  8, A0, A1); CS(RB, 5, 16, 1,  9, A0, A1); \
    CS(RC, 6, 16, 1, 10, A0, A1); CS(RD, 7, 16, 1, 11, A0, A1); \
    CS(RA, 8, 16, 1, 12, A0, A1); CS(RB, 9, 16, 1, 13, A0, A1); \
    CS(RC,10, 16, 1, 14, A0, A1); CS(RD,11, 16, 1, 15, A0, A1); \
    CS(RA,12, 16, 0, 0, A0, A1);  CS(RB,13, 12, 0, 0, A0, A1); \
    CS(RC,14,  8, 0, 0, A0, A1);  CS(RD,15,  4, 0, 0, A0, A1); \
} while (0)

    // ---- prologue: prime dir0 step 0 with the exact steady-state queue shape
    const unsigned* pb0 = h_tag + ((size_t)(0 * 2 + 0) * 32 + brow) * 1024 + lk8 * 2;
    {
        const unsigned* xpb0 = XP + ((((size_t)0 * 64 + blk) * 512 + 0) * 32 + b_own) * 32;
        LDP4(xp0A, xpb0 + jl_own * 4);
        LDP4(xp0B, xpb0 + (jl_own + 4) * 4);
        ISSUE_K(RA, pb0, 0); ISSUE_K(RB, pb0, 1);
        ISSUE_K(RC, pb0, 2); ISSUE_K(RD, pb0, 3);
        // 4 tail stores mimicking the steady epilogue (idempotent re-publish)
        #pragma unroll
        for (int v = 0; v < 2; ++v) {
            int j = j0 + jl_own + v * 4;
            ushort a = bf16_rne(hr0[v]), bq = bf16_rne(hr0[v] - bf16_to_f(a));
            unsigned pay = (unsigned)a | ((unsigned)bq << 16);
            st_tag2(h_tag + ((size_t)(0 * 2 + 0) * 32 + b_own) * 1024 + j * 2, pay, pay ^ keyof(0));
            a = bf16_rne(hr1[v]); bq = bf16_rne(hr1[v] - bf16_to_f(a));
            pay = (unsigned)a | ((unsigned)bq << 16);
            st_tag2(h_tag + ((size_t)(0 * 2 + 1) * 32 + b_own) * 1024 + j * 2, pay, pay ^ keyof(0));
        }
    }

    for (int s = 0; s < TT; ++s) {
        const int p = s & 1, pn = p ^ 1;
        const unsigned key = keyof(s), nkey = keyof(s + 1);
        const int t1 = TT - 1 - s;

        // P1: consume dir0 h[s]
        f32x4 a00 = {0.f,0.f,0.f,0.f}, a01 = a00;
        CONSUME_DIR(pb0, 0, a00, a01);

        // P2: drain, issue dir1's XP + first ring
        WAIT_VM(0); clean = true;
        const unsigned* xpb1 = XP + ((((size_t)1 * 64 + blk) * 512 + t1) * 32 + b_own) * 32;
        LDP4(xp1A, xpb1 + jl_own * 4);
        LDP4(xp1B, xpb1 + (jl_own + 4) * 4);
        const unsigned* pb1 = h_tag + ((size_t)(p * 2 + 1) * 32 + brow) * 1024 + lk8 * 2;
        ISSUE_K(RA, pb1, 0); ISSUE_K(RB, pb1, 1);
        ISSUE_K(RC, pb1, 2); ISSUE_K(RD, pb1, 3);

        // P3: dir0 epilogue (publish h0[s+1]) — its MALL latency hides under P4
        epilogue(0, s, pn, nkey, xp0A, xp0B, a00, a01, cr0, hr0);

        // P4: consume dir1 h[s]
        f32x4 a10 = {0.f,0.f,0.f,0.f}, a11 = a10;
        CONSUME_DIR(pb1, 65536, a10, a11);

        // P5: drain, issue dir0's next XP + first ring (consumed next iter)
        WAIT_VM(0); clean = true;
        if (s + 1 < TT) {
            const unsigned* xpb0 = XP + ((((size_t)0 * 64 + blk) * 512 + (s + 1)) * 32 + b_own) * 32;
            LDP4(xp0A, xpb0 + jl_own * 4);
            LDP4(xp0B, xpb0 + (jl_own + 4) * 4);
            pb0 = h_tag + ((size_t)(pn * 2 + 0) * 32 + brow) * 1024 + lk8 * 2;
            ISSUE_K(RA, pb0, 0); ISSUE_K(RB, pb0, 1);
            ISSUE_K(RC, pb0, 2); ISSUE_K(RD, pb0, 3);
        }

        // P6: dir1 epilogue (publish h1[s+1]) — latency hides under next P1
        epilogue(1, t1, pn, nkey, xp1A, xp1B, a10, a11, cr1, hr1);
    }

    // finals: out = y[512,32,1024] ++ h_out[2,32,512] ++ c_out[2,32,512]
    #pragma unroll
    for (int v = 0; v < 2; ++v) {
        int j = j0 + jl_own + v * 4;
        out[16777216 +         (0 * BB + b_own) * HH + j] = hr0[v];
        out[16777216 + 32768 + (0 * BB + b_own) * HH + j] = cr0[v];
        out[16777216 +         (1 * BB + b_own) * HH + j] = hr1[v];
        out[16777216 + 32768 + (1 * BB + b_own) * HH + j] = cr1[v];
    }
}

extern "C" void kernel_launch(void* const* d_in, const int* in_sizes, int n_in,
                              void* d_out, int out_size, void* d_ws, size_t ws_size,
                              hipStream_t stream) {
    const float* x    = (const float*)d_in[0];
    const float* h0   = (const float*)d_in[1];
    const float* c0   = (const float*)d_in[2];
    const float* W_ih = (const float*)d_in[3];
    const float* b_ih = (const float*)d_in[4];
    const float* W_hh = (const float*)d_in[5];
    const float* b_hh = (const float*)d_in[6];
    float* out = (float*)d_out;

    // ws: XP (256 MiB packed u32) | h_tag (2 parity x 2 dir x 32 b x 512 j x 8B)
    unsigned* XP    = (unsigned*)d_ws;
    unsigned* h_tag = XP + (size_t)2 * 64 * 512 * 32 * 32;

    xpre_gemm<<<4096, 256, 0, stream>>>(x, W_ih, XP);

    void* args[] = { &h0, &c0, &W_hh, &b_ih, &b_hh, &XP, &h_tag, &out };
    hipLaunchCooperativeKernel((void*)lstm_persist, dim3(NBLK), dim3(NTHR),
                               args, 0, stream);
}

// Round 7
// 3600.874 us; speedup vs baseline: 1.8864x; 1.8864x over previous
//
#include <hip/hip_runtime.h>

// Problem constants (T,B,D,H = 512,32,512,512; bidirectional)
#define TT    512
#define BB    32
#define HH    512
#define NBDIR 64           // blocks per direction; each owns 8 hidden units (32 gate rows)
#define NTHR  128          // 2 waves

typedef __attribute__((ext_vector_type(8))) short short8;
typedef __attribute__((ext_vector_type(4))) float f32x4;
typedef __attribute__((ext_vector_type(4))) unsigned u32x4;
typedef __attribute__((ext_vector_type(2))) unsigned u32x2;

#define SELH 0x05040100u   // v_perm: hi bf16 plane of 2 packed elems
#define SELL 0x07060302u   // lo bf16 plane

__device__ __forceinline__ ushort bf16_rne(float v) {
    unsigned u = __builtin_bit_cast(unsigned, v);
    unsigned r = u + 0x7FFFu + ((u >> 16) & 1u);
    return (ushort)(r >> 16);
}
__device__ __forceinline__ float bf16_to_f(ushort h) {
    unsigned u = ((unsigned)h) << 16;
    return __builtin_bit_cast(float, u);
}
__device__ __forceinline__ float xpf(unsigned u) {
    return bf16_to_f((ushort)(u & 0xFFFF)) + bf16_to_f((ushort)(u >> 16));
}

// coherent loads/stores (bypass L1/L2 -> MALL)
#define LDT(dst, PB, OFF) \
    asm volatile("global_load_dwordx4 %0, %1, off offset:%c2 sc0 sc1" \
                 : "=v"(dst) : "v"(PB), "i"(OFF) : "memory")
#define LDP4(dst, P) \
    asm volatile("global_load_dwordx4 %0, %1, off" : "=v"(dst) : "v"(P) : "memory")
// flag poll load: dwordx4 + immediate drain (also drains in-flight XP - fine)
#define LDF4(dst, P) \
    asm volatile("global_load_dwordx4 %0, %1, off sc0 sc1\n\t" \
                 "s_waitcnt vmcnt(0)" : "=v"(dst) : "v"(P) : "memory")
#define WAIT_VM(N) do { asm volatile("s_waitcnt vmcnt(" #N ")" ::: "memory"); \
                        __builtin_amdgcn_sched_barrier(0); } while (0)

__device__ __forceinline__ void st_u32(unsigned* p, unsigned v) {
    asm volatile("global_store_dword %0, %1, off sc0 sc1" :: "v"(p), "v"(v) : "memory");
}
__device__ __forceinline__ void st_f(float* p, float v) {
    asm volatile("global_store_dword %0, %1, off" :: "v"(p), "v"(v) : "memory");
}

// one k-chunk: 4 k-steps x 8 packed elems/lane = 8 x dwordx4 (128 k-elems)
#define ISSUE_KB(BUF, PB, KB) do { \
    LDT(BUF[0], PB, (KB)*512+  0); LDT(BUF[1], PB, (KB)*512+ 16); \
    LDT(BUF[2], PB, (KB)*512+128); LDT(BUF[3], PB, (KB)*512+144); \
    LDT(BUF[4], PB, (KB)*512+256); LDT(BUF[5], PB, (KB)*512+272); \
    LDT(BUF[6], PB, (KB)*512+384); LDT(BUF[7], PB, (KB)*512+400); \
} while (0)

// ---------------------------------------------------------------------------
// Pre-pass GEMM: XP[d][blk][t][b][slot] = packed bf16 hi|lo of (x . W_ih^T),
// slot = jl*4+q for gate g = q*512 + blk*8 + jl. Also zeroes the flags.
// ---------------------------------------------------------------------------
__global__ void __launch_bounds__(256, 1)
xpre_gemm(const float* __restrict__ x, const float* __restrict__ W_ih,
          unsigned* __restrict__ XP, unsigned* __restrict__ flags) {
    __shared__ __align__(16) char sA[32768];
    __shared__ __align__(16) char sB[32768];
    const int tid = threadIdx.x;
    const int bid = blockIdx.x;
    if (bid == 0) flags[tid] = 0u;
    const int d  = bid & 1;
    const int nt = (bid >> 1) & 15;
    const int mt = bid >> 5;
    const int lane = tid & 63, wid = tid >> 6;
    const int wm = wid >> 1, wn = wid & 1;
    const int lr = lane & 15, lk8 = (lane >> 4) * 8;

    f32x4 acc[16];
    #pragma unroll
    for (int i = 0; i < 16; ++i) acc[i] = (f32x4){0.f, 0.f, 0.f, 0.f};

    const float* Ab = x + (size_t)(mt * 128) * 512;
    const float* Bb = W_ih + ((size_t)d * 2048 + nt * 128) * 512;

    for (int kc = 0; kc < 8; ++kc) {
        #pragma unroll
        for (int i = 0; i < 8; ++i) {
            int f = i * 256 + tid;
            int row = f >> 4, fc = f & 15;
            int byte = (row * 128 + fc * 8) ^ ((row & 7) << 4);
            f32x4 va = *(const f32x4*)(Ab + (size_t)row * 512 + kc * 64 + fc * 4);
            f32x4 vb = *(const f32x4*)(Bb + (size_t)row * 512 + kc * 64 + fc * 4);
            ushort h0 = bf16_rne(va[0]), h1 = bf16_rne(va[1]), h2 = bf16_rne(va[2]), h3 = bf16_rne(va[3]);
            ushort l0 = bf16_rne(va[0] - bf16_to_f(h0)), l1 = bf16_rne(va[1] - bf16_to_f(h1));
            ushort l2 = bf16_rne(va[2] - bf16_to_f(h2)), l3 = bf16_rne(va[3] - bf16_to_f(h3));
            *(u32x2*)(sA + byte)         = (u32x2){ (unsigned)h0 | ((unsigned)h1 << 16),
                                                    (unsigned)h2 | ((unsigned)h3 << 16) };
            *(u32x2*)(sA + 16384 + byte) = (u32x2){ (unsigned)l0 | ((unsigned)l1 << 16),
                                                    (unsigned)l2 | ((unsigned)l3 << 16) };
            h0 = bf16_rne(vb[0]); h1 = bf16_rne(vb[1]); h2 = bf16_rne(vb[2]); h3 = bf16_rne(vb[3]);
            l0 = bf16_rne(vb[0] - bf16_to_f(h0)); l1 = bf16_rne(vb[1] - bf16_to_f(h1));
            l2 = bf16_rne(vb[2] - bf16_to_f(h2)); l3 = bf16_rne(vb[3] - bf16_to_f(h3));
            *(u32x2*)(sB + byte)         = (u32x2){ (unsigned)h0 | ((unsigned)h1 << 16),
                                                    (unsigned)h2 | ((unsigned)h3 << 16) };
            *(u32x2*)(sB + 16384 + byte) = (u32x2){ (unsigned)l0 | ((unsigned)l1 << 16),
                                                    (unsigned)l2 | ((unsigned)l3 << 16) };
        }
        __syncthreads();
        #pragma unroll
        for (int ks = 0; ks < 2; ++ks) {
            short8 bh[4], bl[4];
            #pragma unroll
            for (int ns = 0; ns < 4; ++ns) {
                int brow = wn * 64 + ns * 16 + lr;
                int byte = (brow * 128 + (ks * 32 + lk8) * 2) ^ ((brow & 7) << 4);
                bh[ns] = *(const short8*)(sB + byte);
                bl[ns] = *(const short8*)(sB + 16384 + byte);
            }
            #pragma unroll
            for (int ms = 0; ms < 4; ++ms) {
                int arow = wm * 64 + ms * 16 + lr;
                int byte = (arow * 128 + (ks * 32 + lk8) * 2) ^ ((arow & 7) << 4);
                short8 ah = *(const short8*)(sA + byte);
                short8 al = *(const short8*)(sA + 16384 + byte);
                #pragma unroll
                for (int ns = 0; ns < 4; ++ns) {
                    acc[ms*4+ns] = __builtin_amdgcn_mfma_f32_16x16x32_bf16(ah, bh[ns], acc[ms*4+ns], 0,0,0);
                    acc[ms*4+ns] = __builtin_amdgcn_mfma_f32_16x16x32_bf16(al, bh[ns], acc[ms*4+ns], 0,0,0);
                    acc[ms*4+ns] = __builtin_amdgcn_mfma_f32_16x16x32_bf16(ah, bl[ns], acc[ms*4+ns], 0,0,0);
                }
            }
        }
        __syncthreads();
    }
    #pragma unroll
    for (int ms = 0; ms < 4; ++ms)
    #pragma unroll
    for (int ns = 0; ns < 4; ++ns)
    #pragma unroll
    for (int r = 0; r < 4; ++r) {
        float v = acc[ms*4+ns][r];
        int m = mt * 128 + wm * 64 + ms * 16 + (lane >> 4) * 4 + r;
        int n = nt * 128 + wn * 64 + ns * 16 + lr;
        int t = m >> 5, b = m & 31;
        int q = n >> 9, rem = n & 511, bk = rem >> 3, jl = rem & 7;
        ushort hi = bf16_rne(v);
        ushort lo = bf16_rne(v - bf16_to_f(hi));
        XP[((((size_t)d * 64 + bk) * 512 + t) * 32 + b) * 32 + (jl * 4 + q)] =
            (unsigned)hi | ((unsigned)lo << 16);
    }
}

// ---------------------------------------------------------------------------
// Persistent recurrence, r3 flag protocol + low-contention polling.
// 128 blocks (2 dir x 64), 128 thr (2 waves). Block owns 8 j (32 gate slots);
// W_hh slice stationary in LDS (64 KB, swizzled bf16 hi/lo). Per step:
// XP prefetch -> 16-lane dwordx4 flag poll -> pipelined sc0sc1 h loads (2-deep
// vmcnt ledger) -> 96 MFMA/wave -> sC epilogue -> publish h + flag.
// ---------------------------------------------------------------------------
__global__ void __launch_bounds__(NTHR, 1)
lstm_persist(const float* __restrict__ h0, const float* __restrict__ c0,
             const float* __restrict__ W_hh, const float* __restrict__ b_ih,
             const float* __restrict__ b_hh, const unsigned* __restrict__ XP,
             unsigned* __restrict__ h_buf, unsigned* __restrict__ flags,
             float* __restrict__ out) {
    __shared__ __align__(16) char sW[65536];   // [32 slots][512 k] hi 32K + lo 32K
    __shared__ float sC[32][33];
    __shared__ float sBias[32];

    const int tid = threadIdx.x, bid = blockIdx.x;
    const int d = bid >> 6, blk = bid & 63, j0 = blk * 8;

    for (int idx = tid; idx < 32 * 512; idx += NTHR) {
        int r = idx >> 9, col = idx & 511;
        int jl = r >> 2, q = r & 3, g = q * 512 + j0 + jl;
        float v = W_hh[((size_t)d * 2048 + g) * 512 + col];
        ushort hi = bf16_rne(v), lo = bf16_rne(v - bf16_to_f(hi));
        int byte = (r * 1024 + col * 2) ^ ((r & 7) << 4);
        *(ushort*)(sW + byte)         = hi;
        *(ushort*)(sW + 32768 + byte) = lo;
    }
    if (tid < 32) {
        int jl = tid >> 2, q = tid & 3, g = q * 512 + j0 + jl;
        sBias[tid] = b_ih[d * 2048 + g] + b_hh[d * 2048 + g];
    }

    // owned state: thread (b_own, jl_own) handles jl = jl_own and jl_own+4
    const int b_own = tid >> 2, jl_own = tid & 3;
    float c_reg[2], h_reg[2];
    #pragma unroll
    for (int v = 0; v < 2; ++v) {
        int j = j0 + jl_own + v * 4;
        c_reg[v] = c0[(d * BB + b_own) * HH + j];
        h_reg[v] = h0[(d * BB + b_own) * HH + j];
        ushort hi = bf16_rne(h_reg[v]), lo = bf16_rne(h_reg[v] - bf16_to_f(hi));
        st_u32(h_buf + ((size_t)(0 * 2 + d) * 32 + b_own) * 512 + j,
               (unsigned)hi | ((unsigned)lo << 16));
    }
    __syncthreads();   // compiler emits vmcnt(0) drain before barrier
    if (tid == 0) st_u32(flags + d * NBDIR + blk, 1u);

    const int lane = tid & 63, w = tid >> 6;
    const int lr = lane & 15, lk8 = (lane >> 4) * 8;
    const int brow = w * 16 + lr;          // A-rows: waves disjoint (16 b each)

    u32x4 A[8], B[8];

    for (int s = 0; s < TT; ++s) {
        const int t_eff = d ? (TT - 1 - s) : s;
        const int p = s & 1;

        // XP prefetch (plain cached; in flight during the poll)
        const unsigned* xpb =
            XP + ((((size_t)d * 64 + blk) * 512 + t_eff) * 32 + b_own) * 32;
        u32x4 xpA, xpB;
        LDP4(xpA, xpb + jl_own * 4);
        LDP4(xpB, xpb + (jl_own + 4) * 4);

        // low-contention poll: 16 lanes x dwordx4 cover all 64 own-dir flags
        if (tid < 16) {
            const unsigned* fp = flags + d * NBDIR + tid * 4;
            const unsigned tgt = (unsigned)s + 1u;
            for (;;) {
                u32x4 f;
                LDF4(f, fp);
                bool ok = f[0] >= tgt && f[1] >= tgt && f[2] >= tgt && f[3] >= tgt;
                if ((__ballot(ok) & 0xFFFFull) == 0xFFFFull) break;
                __builtin_amdgcn_s_sleep(1);
            }
        }
        __syncthreads();
        WAIT_VM(0);    // ledger baseline: XP + stores + poll loads retired

        // pipelined consume: 4 chunks of 128 k, 2-deep
        const unsigned* pb =
            h_buf + ((size_t)(p * 2 + d) * 32 + brow) * 512 + lk8;
        f32x4 acc0 = {0.f, 0.f, 0.f, 0.f}, acc1 = acc0;

        auto mfma_kb = [&](const u32x4* buf, int kb) {
            #pragma unroll
            for (int ks = 0; ks < 4; ++ks) {
                unsigned q0 = buf[ks*2][0],   q1 = buf[ks*2][1];
                unsigned q2 = buf[ks*2][2],   q3 = buf[ks*2][3];
                unsigned q4 = buf[ks*2+1][0], q5 = buf[ks*2+1][1];
                unsigned q6 = buf[ks*2+1][2], q7 = buf[ks*2+1][3];
                u32x4 hh = { __builtin_amdgcn_perm(q1, q0, SELH), __builtin_amdgcn_perm(q3, q2, SELH),
                             __builtin_amdgcn_perm(q5, q4, SELH), __builtin_amdgcn_perm(q7, q6, SELH) };
                u32x4 ll = { __builtin_amdgcn_perm(q1, q0, SELL), __builtin_amdgcn_perm(q3, q2, SELL),
                             __builtin_amdgcn_perm(q5, q4, SELL), __builtin_amdgcn_perm(q7, q6, SELL) };
                short8 ah = __builtin_bit_cast(short8, hh);
                short8 al = __builtin_bit_cast(short8, ll);
                int k2 = (kb * 128 + ks * 32 + lk8) * 2;
                {   int byte = (lr * 1024 + k2) ^ ((lr & 7) << 4);
                    short8 bh = *(const short8*)(sW + byte);
                    short8 bl = *(const short8*)(sW + 32768 + byte);
                    acc0 = __builtin_amdgcn_mfma_f32_16x16x32_bf16(ah, bh, acc0, 0,0,0);
                    acc0 = __builtin_amdgcn_mfma_f32_16x16x32_bf16(al, bh, acc0, 0,0,0);
                    acc0 = __builtin_amdgcn_mfma_f32_16x16x32_bf16(ah, bl, acc0, 0,0,0);
                }
                {   int srow = 16 + lr;
                    int byte = (srow * 1024 + k2) ^ ((srow & 7) << 4);
                    short8 bh = *(const short8*)(sW + byte);
                    short8 bl = *(const short8*)(sW + 32768 + byte);
                    acc1 = __builtin_amdgcn_mfma_f32_16x16x32_bf16(ah, bh, acc1, 0,0,0);
                    acc1 = __builtin_amdgcn_mfma_f32_16x16x32_bf16(al, bh, acc1, 0,0,0);
                    acc1 = __builtin_amdgcn_mfma_f32_16x16x32_bf16(ah, bl, acc1, 0,0,0);
                }
            }
        };

        ISSUE_KB(A, pb, 0);
        ISSUE_KB(B, pb, 1);
        WAIT_VM(8);  mfma_kb(A, 0);
        ISSUE_KB(A, pb, 2);
        WAIT_VM(8);  mfma_kb(B, 1);
        ISSUE_KB(B, pb, 3);
        WAIT_VM(8);  mfma_kb(A, 2);
        WAIT_VM(0);  mfma_kb(B, 3);

        // C layout: row = b (wave-local), col = slot
        #pragma unroll
        for (int r = 0; r < 4; ++r) {
            int row = w * 16 + (lane >> 4) * 4 + r;
            sC[row][lr]      = acc0[r];
            sC[row][16 + lr] = acc1[r];
        }
        __syncthreads();

        const int pn = (s + 1) & 1;
        #pragma unroll
        for (int v = 0; v < 2; ++v) {
            int jl = jl_own + v * 4;
            const u32x4& xp = v ? xpB : xpA;
            float gi = sC[b_own][jl*4+0] + sBias[jl*4+0] + xpf(xp[0]);
            float gf = sC[b_own][jl*4+1] + sBias[jl*4+1] + xpf(xp[1]);
            float gg = sC[b_own][jl*4+2] + sBias[jl*4+2] + xpf(xp[2]);
            float go = sC[b_own][jl*4+3] + sBias[jl*4+3] + xpf(xp[3]);
            float ig = 1.f / (1.f + expf(-gi));
            float fg = 1.f / (1.f + expf(-gf));
            float gt = tanhf(gg);
            float og = 1.f / (1.f + expf(-go));
            c_reg[v] = fg * c_reg[v] + ig * gt;
            h_reg[v] = og * tanhf(c_reg[v]);

            int j = j0 + jl;
            ushort hi = bf16_rne(h_reg[v]), lo = bf16_rne(h_reg[v] - bf16_to_f(hi));
            st_u32(h_buf + ((size_t)(pn * 2 + d) * 32 + b_own) * 512 + j,
                   (unsigned)hi | ((unsigned)lo << 16));
            st_f(out + ((size_t)t_eff * BB + b_own) * 1024 + d * 512 + j, h_reg[v]);
        }
        __syncthreads();   // drains this block's h stores before flag publish
        if (tid == 0) st_u32(flags + d * NBDIR + blk, (unsigned)s + 2u);
    }

    // finals: out = y[512,32,1024] ++ h_out[2,32,512] ++ c_out[2,32,512]
    #pragma unroll
    for (int v = 0; v < 2; ++v) {
        int j = j0 + jl_own + v * 4;
        out[16777216 +         (d * BB + b_own) * HH + j] = h_reg[v];
        out[16777216 + 32768 + (d * BB + b_own) * HH + j] = c_reg[v];
    }
}

extern "C" void kernel_launch(void* const* d_in, const int* in_sizes, int n_in,
                              void* d_out, int out_size, void* d_ws, size_t ws_size,
                              hipStream_t stream) {
    const float* x    = (const float*)d_in[0];
    const float* h0   = (const float*)d_in[1];
    const float* c0   = (const float*)d_in[2];
    const float* W_ih = (const float*)d_in[3];
    const float* b_ih = (const float*)d_in[4];
    const float* W_hh = (const float*)d_in[5];
    const float* b_hh = (const float*)d_in[6];
    float* out = (float*)d_out;

    // ws: XP (256 MiB packed u32) | h_buf (2 parity x 2 dir x 32 x 512 u32) | flags
    unsigned* XP    = (unsigned*)d_ws;
    unsigned* h_buf = XP + (size_t)2 * 64 * 512 * 32 * 32;
    unsigned* flags = h_buf + 4 * 32 * 512;

    xpre_gemm<<<4096, 256, 0, stream>>>(x, W_ih, XP, flags);

    void* args[] = { &h0, &c0, &W_hh, &b_ih, &b_hh, &XP, &h_buf, &flags, &out };
    hipLaunchCooperativeKernel((void*)lstm_persist, dim3(2 * NBDIR), dim3(NTHR),
                               args, 0, stream);
}